// Round 2
// baseline (484.667 us; speedup 1.0000x reference)
//
#include <hip/hip_runtime.h>
#include <stdint.h>

typedef unsigned short u16;
typedef __attribute__((ext_vector_type(8))) short bf16x8;
typedef __attribute__((ext_vector_type(4))) float f32x4;

#define C_IN    64
#define K_OUT   128
#define HW      112
#define HW2     (HW * HW)   // 12544
#define CPH     36          // half-channel pitch (bf16 elems): 32 data + 4 pad
#define NW      114         // w' + 1 in [0,114): includes left/right zero pad
#define THREADS 256

// round-to-nearest-even fp32 -> bf16 (finite inputs)
__device__ __forceinline__ u16 f2bf(float f) {
  union { float f; uint32_t u; } x; x.f = f;
  return (u16)((x.u + 0x7FFFu + ((x.u >> 16) & 1u)) >> 16);
}

// OIHW fp32 weights -> bf16 wt[(rs*K_OUT + kout)*C_IN + c]  (c contiguous)
__global__ void prep_weights(const float* __restrict__ w, u16* __restrict__ wt) {
  int idx = blockIdx.x * 256 + threadIdx.x;
  if (idx >= K_OUT * C_IN * 9) return;
  int c    = idx & (C_IN - 1);
  int kout = (idx >> 6) & (K_OUT - 1);
  int rs   = idx >> 13;
  wt[idx] = f2bf(w[(kout * C_IN + c) * 9 + rs]);
}

// Channel-split (c 0..31, then 32..63) halves LDS to 24.6KB -> 6 blocks/CU
// (24 waves, 75% occupancy) for latency hiding. Weights stay in registers
// (L2-resident wt), with explicit rs+1 prefetch. CPH=36 makes the B-row
// lane stride 72B = 18 banks -> 16 distinct start banks (conflict-free-ish
// reads); staging writes are exact 2-way (free).
__global__ __launch_bounds__(THREADS, 6) void conv3x3(
    const float* __restrict__ x, const u16* __restrict__ wt,
    const float* __restrict__ bias, float* __restrict__ out) {
  // X half-tile: [r][w'+1][c'], bf16, c' contiguous (pitch CPH). 3*114*36*2 = 24624 B
  __shared__ u16 Xs[3][NW][CPH];

  const int tid = threadIdx.x;

  // XCD-chunked swizzle: 3584 blocks % 8 XCDs == 0; adjacent-h blocks
  // (sharing 2/3 input rows) land on the same XCD L2.
  const int bid = blockIdx.x;
  const int lb  = (bid & 7) * 448 + (bid >> 3);
  const int n = lb / HW;
  const int h = lb % HW;

  // ---- zero once: pad columns + out-of-range h rows (persist both phases) ----
  if (tid < 96) {
    const int seg  = tid >> 4;               // 0..5 -> (r, left/right)
    const int cd   = (tid & 15) * 2;         // c' (even)
    const int r    = seg >> 1;
    const int wcol = (seg & 1) ? (NW - 1) : 0;
    *(uint32_t*)&Xs[r][wcol][cd] = 0u;
  }
  if (h == 0) {
    uint32_t* p = (uint32_t*)&Xs[0][0][0];
    for (int t = tid; t < NW * (CPH / 2); t += THREADS) p[t] = 0u;
  } else if (h == HW - 1) {
    uint32_t* p = (uint32_t*)&Xs[2][0][0];
    for (int t = tid; t < NW * (CPH / 2); t += THREADS) p[t] = 0u;
  }

  const int lane = tid & 63;
  const int wave = tid >> 6;
  const int quad = lane >> 4;
  const int l15  = lane & 15;
  const int kb   = wave * 32;  // wave's kout base (32 channels per wave)

  f32x4 acc[2][7];
#pragma unroll
  for (int i = 0; i < 2; ++i)
#pragma unroll
    for (int j = 0; j < 7; ++j) acc[i][j] = (f32x4){0.f, 0.f, 0.f, 0.f};

  const float* xn = x + (size_t)n * C_IN * HW2;

  for (int chalf = 0; chalf < 2; ++chalf) {
    // ---- stage X rows h-1..h+1, channels chalf*32..+31, as bf16 [w'][c'] ----
    // Task map: 16 cp x 28 w4 x 3 r = 1344. A wave's 16-lane groups write 16
    // distinct c' at fixed w' -> LDS bank (18*w'+cp)%32, 2-way (free). Global:
    // 16B/lane; each 64B line fully consumed by neighboring w4 tasks.
    {
      const float* xh = xn + (size_t)(chalf * 32) * HW2;
#pragma unroll 1
      for (int it = 0; it < 6; ++it) {
        const int task = tid + it * THREADS;
        if (task < 3 * 28 * 16) {
          const int cp   = task & 15;
          const int rest = task >> 4;        // 0..83
          const int w4   = rest % 28;
          const int r    = rest / 28;
          const int row  = h + r - 1;
          if (row >= 0 && row < HW) {
            const float* xrow = xh + (size_t)(2 * cp) * HW2 + (size_t)row * HW + w4 * 4;
            const float4 va = *(const float4*)(xrow);
            const float4 vb = *(const float4*)(xrow + HW2);
            const int wb = 1 + w4 * 4;
            const int c  = 2 * cp;
            *(uint32_t*)&Xs[r][wb + 0][c] = (uint32_t)f2bf(va.x) | ((uint32_t)f2bf(vb.x) << 16);
            *(uint32_t*)&Xs[r][wb + 1][c] = (uint32_t)f2bf(va.y) | ((uint32_t)f2bf(vb.y) << 16);
            *(uint32_t*)&Xs[r][wb + 2][c] = (uint32_t)f2bf(va.z) | ((uint32_t)f2bf(vb.z) << 16);
            *(uint32_t*)&Xs[r][wb + 3][c] = (uint32_t)f2bf(va.w) | ((uint32_t)f2bf(vb.w) << 16);
          }
        }
      }
    }
    __syncthreads();  // staging (and, at chalf=0, zero-fill) complete

    // ---- compute: 9 rs x 7 w7 x 2 mt MFMAs, K=32 = this phase's channels ----
    {
      const int cof = chalf * 32 + quad * 8;
      const u16* w0p = wt + (size_t)(kb + l15) * C_IN + cof;
      const u16* w1p = wt + (size_t)(kb + 16 + l15) * C_IN + cof;
      bf16x8 a0 = *(const bf16x8*)(w0p);
      bf16x8 a1 = *(const bf16x8*)(w1p);
#pragma unroll 1
      for (int rs = 0; rs < 9; ++rs) {
        const int nrs = (rs < 8) ? rs + 1 : 8;
        const bf16x8 na0 = *(const bf16x8*)(w0p + nrs * (K_OUT * C_IN));
        const bf16x8 na1 = *(const bf16x8*)(w1p + nrs * (K_OUT * C_IN));
        const int r = rs / 3;
        const int s = rs - r * 3;
        const u16* xrow = &Xs[r][l15 + s][quad * 8];
#pragma unroll
        for (int w7 = 0; w7 < 7; ++w7) {
          const bf16x8 b = *(const bf16x8*)(xrow + w7 * 16 * CPH);
          acc[0][w7] = __builtin_amdgcn_mfma_f32_16x16x32_bf16(a0, b, acc[0][w7], 0, 0, 0);
          acc[1][w7] = __builtin_amdgcn_mfma_f32_16x16x32_bf16(a1, b, acc[1][w7], 0, 0, 0);
        }
        a0 = na0; a1 = na1;
      }
    }
    if (chalf == 0) __syncthreads();  // all reads done before phase-1 restage
  }

  // ---- epilogue: D row = quad*4 + reg (kout), col = l15 (w) ----
  float* on = out + (size_t)n * K_OUT * HW2 + (size_t)h * HW;
#pragma unroll
  for (int mt = 0; mt < 2; ++mt) {
#pragma unroll
    for (int rg = 0; rg < 4; ++rg) {
      const int kout = kb + mt * 16 + quad * 4 + rg;
      const float bv = bias[kout];
      float* orow = on + (size_t)kout * HW2;
#pragma unroll
      for (int w7 = 0; w7 < 7; ++w7) {
        orow[w7 * 16 + l15] = acc[mt][w7][rg] + bv;
      }
    }
  }
}

extern "C" void kernel_launch(void* const* d_in, const int* in_sizes, int n_in,
                              void* d_out, int out_size, void* d_ws, size_t ws_size,
                              hipStream_t stream) {
  const float* x  = (const float*)d_in[0];
  const float* w  = (const float*)d_in[1];
  const float* bi = (const float*)d_in[2];
  float* out = (float*)d_out;
  u16* wt = (u16*)d_ws;  // needs 9*128*64*2 = 147456 B of scratch

  prep_weights<<<(K_OUT * C_IN * 9 + 255) / 256, 256, 0, stream>>>(w, wt);
  conv3x3<<<32 * HW, THREADS, 0, stream>>>(x, wt, bi, out);
}

// Round 3
// 429.830 us; speedup vs baseline: 1.1276x; 1.1276x over previous
//
#include <hip/hip_runtime.h>
#include <stdint.h>

typedef unsigned short u16;
typedef __attribute__((ext_vector_type(8))) short bf16x8;
typedef __attribute__((ext_vector_type(4))) float f32x4;

#define C_IN    64
#define K_OUT   128
#define HW      112
#define HW2     (HW * HW)   // 12544
#define CP      72          // padded channel pitch (bf16 elems): 16B-aligned rows, bank-spread
#define NW      114         // w' + 1 in [0,114): includes left/right zero pad
#define THREADS 512

// round-to-nearest-even fp32 -> bf16 (finite inputs)
__device__ __forceinline__ u16 f2bf(float f) {
  union { float f; uint32_t u; } x; x.f = f;
  return (u16)((x.u + 0x7FFFu + ((x.u >> 16) & 1u)) >> 16);
}

// OIHW fp32 weights -> bf16 wt[(rs*K_OUT + kout)*C_IN + c]  (c contiguous)
__global__ void prep_weights(const float* __restrict__ w, u16* __restrict__ wt) {
  int idx = blockIdx.x * 256 + threadIdx.x;
  if (idx >= K_OUT * C_IN * 9) return;
  int c    = idx & (C_IN - 1);
  int kout = (idx >> 6) & (K_OUT - 1);
  int rs   = idx >> 13;
  wt[idx] = f2bf(w[(kout * C_IN + c) * 9 + rs]);
}

// Per-wave compute+store for w7 in [WLO, WLO+WN). Fully unrolled: 36 L2
// weight loads + WN*18 ds_reads + WN*36 MFMAs as one barrier-free stream
// (R2 showed unroll=1 software pipelining collapses MLP and loses 68%).
template <int WLO, int WN>
__device__ __forceinline__ void do_tile(
    const u16 (&Xs)[3][NW][CP], const u16* __restrict__ wt,
    const float* __restrict__ bias, float* __restrict__ out,
    int n, int h, int kb, int quad, int l15) {
  f32x4 acc[2][WN];
#pragma unroll
  for (int i = 0; i < 2; ++i)
#pragma unroll
    for (int j = 0; j < WN; ++j) acc[i][j] = (f32x4){0.f, 0.f, 0.f, 0.f};

#pragma unroll
  for (int rs = 0; rs < 9; ++rs) {
    const int r = rs / 3;
    const int s = rs - r * 3;
    const u16* wbase = wt + rs * (K_OUT * C_IN);
#pragma unroll
    for (int ch = 0; ch < 2; ++ch) {
      const int c0 = ch * 32 + quad * 8;
      // A[m = l15][k = quad*8 + j] -> wt rows kb+mt*16+l15, c0..c0+7
      const bf16x8 a0 = *(const bf16x8*)(wbase + (kb + l15) * C_IN + c0);
      const bf16x8 a1 = *(const bf16x8*)(wbase + (kb + 16 + l15) * C_IN + c0);
#pragma unroll
      for (int j = 0; j < WN; ++j) {
        const int w7 = WLO + j;
        // B[k = quad*8+jj][nn = l15] -> Xs[r][w + s][c0..c0+7], w = w7*16+l15
        const bf16x8 b = *(const bf16x8*)&Xs[r][w7 * 16 + l15 + s][c0];
        acc[0][j] = __builtin_amdgcn_mfma_f32_16x16x32_bf16(a0, b, acc[0][j], 0, 0, 0);
        acc[1][j] = __builtin_amdgcn_mfma_f32_16x16x32_bf16(a1, b, acc[1][j], 0, 0, 0);
      }
    }
  }

  // epilogue: D row = quad*4 + reg (kout), col = l15 (w)
  float* on = out + (size_t)n * K_OUT * HW2 + (size_t)h * HW;
#pragma unroll
  for (int mt = 0; mt < 2; ++mt) {
#pragma unroll
    for (int rg = 0; rg < 4; ++rg) {
      const int kout = kb + mt * 16 + quad * 4 + rg;
      const float bv = bias[kout];
      float* orow = on + (size_t)kout * HW2;
#pragma unroll
      for (int j = 0; j < WN; ++j) {
        orow[(WLO + j) * 16 + l15] = acc[mt][j][rg] + bv;
      }
    }
  }
}

// 512 threads = 8 waves: wave = (kb in {0,32,64,96}) x (w-half). Same total
// per-block work as the 256-thread version (504 ds_reads, 1008 MFMAs) but
// half the per-wave critical path, and LDS 49.2KB -> 3 blocks/CU = 24 waves
// (75% occupancy) for latency hiding. Weights from L2-resident wt registers.
__global__ __launch_bounds__(THREADS, 6) void conv3x3(
    const float* __restrict__ x, const u16* __restrict__ wt,
    const float* __restrict__ bias, float* __restrict__ out) {
  // X tile: [r][w'+1][c], bf16, c contiguous (pitch CP). 3*114*72*2 = 49248 B
  __shared__ u16 Xs[3][NW][CP];

  const int tid = threadIdx.x;

  // XCD-chunked swizzle: 3584 blocks % 8 XCDs == 0; adjacent-h blocks
  // (sharing 2/3 input rows) land on the same XCD L2.
  const int bid = blockIdx.x;
  const int lb  = (bid & 7) * 448 + (bid >> 3);
  const int n = lb / HW;
  const int h = lb % HW;

  // ---- zero only what the MFMA loop reads but staging never writes ----
  if (tid < 192) {
    const int seg  = tid >> 5;               // 0..5 -> (r, left/right)
    const int cd   = (tid & 31) * 2;         // c (even), dword-packed
    const int r    = seg >> 1;
    const int wcol = (seg & 1) ? (NW - 1) : 0;
    *(uint32_t*)&Xs[r][wcol][cd] = 0u;
  }
  if (h == 0) {
    for (int t = tid; t < NW * 32; t += THREADS)
      *(uint32_t*)&Xs[0][t >> 5][(t & 31) * 2] = 0u;
  } else if (h == HW - 1) {
    for (int t = tid; t < NW * 32; t += THREADS)
      *(uint32_t*)&Xs[2][t >> 5][(t & 31) * 2] = 0u;
  }

  // ---- stage X rows h-1..h+1 as bf16 into [w'][c] ----
  // 32-lane groups write 32 distinct c at fixed w' -> conflict-free LDS
  // writes; 16B/lane global gathers, every 64B line consumed in-block.
  const float* xn = x + (size_t)n * C_IN * HW2;
#pragma unroll
  for (int it = 0; it < 6; ++it) {
    const int task = tid + it * THREADS;     // 3 rows * 28 w4 * 32 cp = 2688
    if (task < 3 * 28 * 32) {
      const int cp   = task & 31;
      const int rest = task >> 5;            // 0..83
      const int w4   = rest % 28;
      const int r    = rest / 28;
      const int row  = h + r - 1;
      if (row >= 0 && row < HW) {
        const float* xrow = xn + (size_t)(2 * cp) * HW2 + (size_t)row * HW + w4 * 4;
        const float4 va = *(const float4*)(xrow);
        const float4 vb = *(const float4*)(xrow + HW2);
        const int wb = 1 + w4 * 4;
        const int c  = 2 * cp;
        *(uint32_t*)&Xs[r][wb + 0][c] = (uint32_t)f2bf(va.x) | ((uint32_t)f2bf(vb.x) << 16);
        *(uint32_t*)&Xs[r][wb + 1][c] = (uint32_t)f2bf(va.y) | ((uint32_t)f2bf(vb.y) << 16);
        *(uint32_t*)&Xs[r][wb + 2][c] = (uint32_t)f2bf(va.z) | ((uint32_t)f2bf(vb.z) << 16);
        *(uint32_t*)&Xs[r][wb + 3][c] = (uint32_t)f2bf(va.w) | ((uint32_t)f2bf(vb.w) << 16);
      }
    }
  }

  __syncthreads();  // the only barrier: staging + zero-fill complete

  const int lane = tid & 63;
  const int wave = tid >> 6;
  const int quad = lane >> 4;
  const int l15  = lane & 15;
  const int kb   = (wave & 3) * 32;  // wave's kout base (32 channels)
  const int wh   = wave >> 2;        // w-half: 0 -> w7 0..3, 1 -> w7 4..6

  if (wh == 0) {
    do_tile<0, 4>(Xs, wt, bias, out, n, h, kb, quad, l15);
  } else {
    do_tile<4, 3>(Xs, wt, bias, out, n, h, kb, quad, l15);
  }
}

extern "C" void kernel_launch(void* const* d_in, const int* in_sizes, int n_in,
                              void* d_out, int out_size, void* d_ws, size_t ws_size,
                              hipStream_t stream) {
  const float* x  = (const float*)d_in[0];
  const float* w  = (const float*)d_in[1];
  const float* bi = (const float*)d_in[2];
  float* out = (float*)d_out;
  u16* wt = (u16*)d_ws;  // needs 9*128*64*2 = 147456 B of scratch

  prep_weights<<<(K_OUT * C_IN * 9 + 255) / 256, 256, 0, stream>>>(w, wt);
  conv3x3<<<32 * HW, THREADS, 0, stream>>>(x, wt, bi, out);
}

// Round 4
// 377.739 us; speedup vs baseline: 1.2831x; 1.1379x over previous
//
#include <hip/hip_runtime.h>
#include <stdint.h>

typedef unsigned short u16;
typedef __attribute__((ext_vector_type(8))) short bf16x8;
typedef __attribute__((ext_vector_type(4))) float f32x4;

#define C_IN    64
#define K_OUT   128
#define HW      112
#define HW2     (HW * HW)   // 12544
#define CP      72          // padded channel pitch (bf16 elems): 16B-aligned rows, bank-spread
#define NW      114         // w' + 1 in [0,114): includes left/right zero pad
#define THREADS 256

// round-to-nearest-even fp32 -> bf16 (finite inputs)
__device__ __forceinline__ u16 f2bf(float f) {
  union { float f; uint32_t u; } x; x.f = f;
  return (u16)((x.u + 0x7FFFu + ((x.u >> 16) & 1u)) >> 16);
}

// OIHW fp32 weights -> bf16 wt[(rs*K_OUT + kout)*C_IN + c]  (c contiguous)
__global__ void prep_weights(const float* __restrict__ w, u16* __restrict__ wt) {
  int idx = blockIdx.x * 256 + threadIdx.x;
  if (idx >= K_OUT * C_IN * 9) return;
  int c    = idx & (C_IN - 1);
  int kout = (idx >> 6) & (K_OUT - 1);
  int rs   = idx >> 13;
  wt[idx] = f2bf(w[(kout * C_IN + c) * 9 + rs]);
}

// R1 skeleton + register-funded MLP. Evidence (R1 vs R2/R3): occupancy 57%
// with 40 VGPRs lost to occupancy 28% with 84 VGPRs -> latency-bound on
// per-wave outstanding loads, not waves. So: launch_bounds(256,2) gives the
// allocator 256 VGPRs; all 18 A-fragments of a 32-channel phase are
// preloaded (18 independent L2 loads in flight), and B-fragments are
// double-buffered across rs (7 ds_reads issued before the 14 MFMAs that
// consume the previous set -> counted lgkmcnt, LDS latency hidden).
__global__ __launch_bounds__(THREADS, 2) void conv3x3(
    const float* __restrict__ x, const u16* __restrict__ wt,
    const float* __restrict__ bias, float* __restrict__ out) {
  // X tile: [r][w'+1][c], bf16, c contiguous (pitch CP). 3*114*72*2 = 49248 B
  __shared__ u16 Xs[3][NW][CP];

  const int tid = threadIdx.x;

  // XCD-chunked swizzle: 3584 blocks % 8 XCDs == 0; adjacent-h blocks
  // (sharing 2/3 input rows) land on the same XCD L2.
  const int bid = blockIdx.x;
  const int lb  = (bid & 7) * 448 + (bid >> 3);
  const int n = lb / HW;
  const int h = lb % HW;

  // ---- zero only what the MFMA loop reads but staging never writes ----
  if (tid < 192) {
    const int seg  = tid >> 5;               // 0..5 -> (r, left/right)
    const int cd   = (tid & 31) * 2;         // c (even), dword-packed
    const int r    = seg >> 1;
    const int wcol = (seg & 1) ? (NW - 1) : 0;
    *(uint32_t*)&Xs[r][wcol][cd] = 0u;
  }
  if (h == 0) {
    for (int t = tid; t < NW * 32; t += THREADS)
      *(uint32_t*)&Xs[0][t >> 5][(t & 31) * 2] = 0u;
  } else if (h == HW - 1) {
    for (int t = tid; t < NW * 32; t += THREADS)
      *(uint32_t*)&Xs[2][t >> 5][(t & 31) * 2] = 0u;
  }

  // ---- stage X rows h-1..h+1 as bf16 into [w'][c] ----
  // 32-lane groups write 32 distinct c at fixed w' -> 2-way (free) LDS
  // writes; 16B/lane global gathers, every 64B line consumed in-block.
  const float* xn = x + (size_t)n * C_IN * HW2;
#pragma unroll
  for (int it = 0; it < 11; ++it) {
    const int task = tid + it * THREADS;     // 3 rows * 28 w4 * 32 cp = 2688
    if (task < 3 * 28 * 32) {
      const int cp   = task & 31;
      const int rest = task >> 5;            // 0..83
      const int w4   = rest % 28;
      const int r    = rest / 28;
      const int row  = h + r - 1;
      if (row >= 0 && row < HW) {
        const float* xrow = xn + (size_t)(2 * cp) * HW2 + (size_t)row * HW + w4 * 4;
        const float4 va = *(const float4*)(xrow);
        const float4 vb = *(const float4*)(xrow + HW2);
        const int wb = 1 + w4 * 4;
        const int c  = 2 * cp;
        *(uint32_t*)&Xs[r][wb + 0][c] = (uint32_t)f2bf(va.x) | ((uint32_t)f2bf(vb.x) << 16);
        *(uint32_t*)&Xs[r][wb + 1][c] = (uint32_t)f2bf(va.y) | ((uint32_t)f2bf(vb.y) << 16);
        *(uint32_t*)&Xs[r][wb + 2][c] = (uint32_t)f2bf(va.z) | ((uint32_t)f2bf(vb.z) << 16);
        *(uint32_t*)&Xs[r][wb + 3][c] = (uint32_t)f2bf(va.w) | ((uint32_t)f2bf(vb.w) << 16);
      }
    }
  }

  __syncthreads();  // the only barrier: staging + zero-fill complete

  const int lane = tid & 63;
  const int wave = tid >> 6;
  const int quad = lane >> 4;
  const int l15  = lane & 15;
  const int kb   = wave * 32;  // wave's kout base (32 channels per wave)

  f32x4 acc[2][7];
#pragma unroll
  for (int i = 0; i < 2; ++i)
#pragma unroll
    for (int j = 0; j < 7; ++j) acc[i][j] = (f32x4){0.f, 0.f, 0.f, 0.f};

#pragma unroll
  for (int ch = 0; ch < 2; ++ch) {
    const int c0 = ch * 32 + quad * 8;
    // One LDS base register; every B address is base + compile-time offset.
    const u16* xb = &Xs[0][l15][c0];
    const u16* wp = wt + (size_t)(kb + l15) * C_IN + c0;

    // ---- preload ALL 18 A-fragments of this phase (72 VGPRs in flight) ----
    bf16x8 A0[9], A1[9];
#pragma unroll
    for (int rs = 0; rs < 9; ++rs) {
      A0[rs] = *(const bf16x8*)(wp + rs * (K_OUT * C_IN));
      A1[rs] = *(const bf16x8*)(wp + rs * (K_OUT * C_IN) + 16 * C_IN);
    }

    // ---- B double-buffer across rs: issue rs+1 reads before rs MFMAs ----
    bf16x8 B[7];
#pragma unroll
    for (int w7 = 0; w7 < 7; ++w7)
      B[w7] = *(const bf16x8*)(xb + (w7 * 16) * CP);  // rs=0: r=0,s=0

#pragma unroll
    for (int rs = 0; rs < 9; ++rs) {
      bf16x8 Bn[7];
      if (rs < 8) {
        const int r1 = (rs + 1) / 3;
        const int s1 = (rs + 1) - r1 * 3;
#pragma unroll
        for (int w7 = 0; w7 < 7; ++w7)
          Bn[w7] = *(const bf16x8*)(xb + (r1 * NW + s1 + w7 * 16) * CP);
      }
#pragma unroll
      for (int w7 = 0; w7 < 7; ++w7) {
        acc[0][w7] = __builtin_amdgcn_mfma_f32_16x16x32_bf16(A0[rs], B[w7], acc[0][w7], 0, 0, 0);
        acc[1][w7] = __builtin_amdgcn_mfma_f32_16x16x32_bf16(A1[rs], B[w7], acc[1][w7], 0, 0, 0);
      }
      if (rs < 8) {
#pragma unroll
        for (int w7 = 0; w7 < 7; ++w7) B[w7] = Bn[w7];  // SSA-renamed, no movs
      }
    }
  }

  // ---- epilogue: D row = quad*4 + reg (kout), col = l15 (w) ----
  float* on = out + (size_t)n * K_OUT * HW2 + (size_t)h * HW;
#pragma unroll
  for (int mt = 0; mt < 2; ++mt) {
#pragma unroll
    for (int rg = 0; rg < 4; ++rg) {
      const int kout = kb + mt * 16 + quad * 4 + rg;
      const float bv = bias[kout];
      float* orow = on + (size_t)kout * HW2;
#pragma unroll
      for (int w7 = 0; w7 < 7; ++w7) {
        orow[w7 * 16 + l15] = acc[mt][w7][rg] + bv;
      }
    }
  }
}

extern "C" void kernel_launch(void* const* d_in, const int* in_sizes, int n_in,
                              void* d_out, int out_size, void* d_ws, size_t ws_size,
                              hipStream_t stream) {
  const float* x  = (const float*)d_in[0];
  const float* w  = (const float*)d_in[1];
  const float* bi = (const float*)d_in[2];
  float* out = (float*)d_out;
  u16* wt = (u16*)d_ws;  // needs 9*128*64*2 = 147456 B of scratch

  prep_weights<<<(K_OUT * C_IN * 9 + 255) / 256, 256, 0, stream>>>(w, wt);
  conv3x3<<<32 * HW, THREADS, 0, stream>>>(x, wt, bi, out);
}